// Round 1
// baseline (762.455 us; speedup 1.0000x reference)
//
#include <hip/hip_runtime.h>

// LowPassFilter: upfirdn2d(x, h⊗h, up=2, down=1, pad=5), sym6 12-tap separable.
// x: [8,64,256,256] f32 -> out: [8,64,511,511] f32.
//
// Derivation: out[o] = sum_j x[j] * h[6 + o - 2j] per axis (true conv of
// zero-upsampled, padded signal). For o = 2p or 2p+1 the contributing inputs
// are j = p-2 .. p+3 (6 taps):
//   even phase weights we[k] = h[10-2k], odd phase wo[k] = h[11-2k].

#define IH 256
#define IW 256
#define OH 511
#define OW 511
#define TILE 64          // output tile edge
#define INT 37           // input tile edge = TILE/2 + 5
#define IN_STRIDE 40     // padded LDS stride for input tile
#define TMP_STRIDE 66    // padded LDS stride for horizontal-pass tile

__global__ __launch_bounds__(256) void lpf_kernel(const float* __restrict__ x,
                                                  float* __restrict__ out) {
    const int ox0 = blockIdx.x * TILE;   // even
    const int oy0 = blockIdx.y * TILE;   // even
    const int plane = blockIdx.z;        // 0..511
    const int px0 = ox0 >> 1;
    const int py0 = oy0 >> 1;

    const float* __restrict__ xp = x + (size_t)plane * (IH * IW);
    float* __restrict__ op = out + (size_t)plane * ((size_t)OH * OW);

    __shared__ float sIn[INT * IN_STRIDE];
    __shared__ float sTmp[INT * TMP_STRIDE];

    const int tid = threadIdx.x;

    // sym6 dec_lo taps (fp32)
    const float h0  =  0.015404109327027373f;
    const float h1  =  0.0034907120842174702f;
    const float h2  = -0.11799011114819057f;
    const float h3  = -0.048311742585633f;
    const float h4  =  0.4910559419267466f;
    const float h5  =  0.787641141030194f;
    const float h6  =  0.3379294217276218f;
    const float h7  = -0.07263752278646252f;
    const float h8  = -0.021060292512300564f;
    const float h9  =  0.04472490177066578f;
    const float h10 =  0.0017677118642428036f;
    const float h11 = -0.007800708325034148f;

    // even phase: we[k] = h[10-2k]; odd phase: wo[k] = h[11-2k]; k=0..5, j=p-2+k
    const float we0 = h10, we1 = h8, we2 = h6, we3 = h4, we4 = h2, we5 = h0;
    const float wo0 = h11, wo1 = h9, wo2 = h7, wo3 = h5, wo4 = h3, wo5 = h1;

    // ---- Stage 0: load 37x37 input patch (zero-padded at borders) ----
    for (int idx = tid; idx < INT * INT; idx += 256) {
        const int r = idx / INT;
        const int c = idx - r * INT;
        const int gr = py0 - 2 + r;
        const int gc = px0 - 2 + c;
        float v = 0.0f;
        if ((unsigned)gr < IH && (unsigned)gc < IW) v = xp[gr * IW + gc];
        sIn[r * IN_STRIDE + c] = v;
    }
    __syncthreads();

    // ---- Stage 1: horizontal polyphase filter -> sTmp[37][64] ----
    {
        const int cx = tid & 31;   // column pair: produces local cols 2cx, 2cx+1
        const int rg = tid >> 5;   // 0..7
        for (int jy = rg; jy < INT; jy += 8) {
            const float* row = &sIn[jy * IN_STRIDE + cx];
            const float a0 = row[0], a1 = row[1], a2 = row[2];
            const float a3 = row[3], a4 = row[4], a5 = row[5];
            float e = a0 * we0;
            e = fmaf(a1, we1, e); e = fmaf(a2, we2, e); e = fmaf(a3, we3, e);
            e = fmaf(a4, we4, e); e = fmaf(a5, we5, e);
            float o = a0 * wo0;
            o = fmaf(a1, wo1, o); o = fmaf(a2, wo2, o); o = fmaf(a3, wo3, o);
            o = fmaf(a4, wo4, o); o = fmaf(a5, wo5, o);
            sTmp[jy * TMP_STRIDE + 2 * cx]     = e;
            sTmp[jy * TMP_STRIDE + 2 * cx + 1] = o;
        }
    }
    __syncthreads();

    // ---- Stage 2: vertical polyphase filter + coalesced stores ----
    {
        const int tx = tid & 63;   // output col within tile (lane)
        const int wy = tid >> 6;   // wave id 0..3
        const int ox = ox0 + tx;
        const bool xok = (ox < OW);
        #pragma unroll
        for (int s = 0; s < 16; s += 2) {
            const int ol = wy * 16 + s;          // local even output row
            const int pl = ol >> 1;              // local tmp row base
            const float* col = &sTmp[pl * TMP_STRIDE + tx];
            const float t0 = col[0 * TMP_STRIDE], t1 = col[1 * TMP_STRIDE];
            const float t2 = col[2 * TMP_STRIDE], t3 = col[3 * TMP_STRIDE];
            const float t4 = col[4 * TMP_STRIDE], t5 = col[5 * TMP_STRIDE];
            float e = t0 * we0;
            e = fmaf(t1, we1, e); e = fmaf(t2, we2, e); e = fmaf(t3, we3, e);
            e = fmaf(t4, we4, e); e = fmaf(t5, we5, e);
            float o = t0 * wo0;
            o = fmaf(t1, wo1, o); o = fmaf(t2, wo2, o); o = fmaf(t3, wo3, o);
            o = fmaf(t4, wo4, o); o = fmaf(t5, wo5, o);
            const int oy = oy0 + ol;
            if (xok) {
                if (oy < OH)     __builtin_nontemporal_store(e, &op[(size_t)oy * OW + ox]);
                if (oy + 1 < OH) __builtin_nontemporal_store(o, &op[(size_t)(oy + 1) * OW + ox]);
            }
        }
    }
}

extern "C" void kernel_launch(void* const* d_in, const int* in_sizes, int n_in,
                              void* d_out, int out_size, void* d_ws, size_t ws_size,
                              hipStream_t stream) {
    const float* x = (const float*)d_in[0];
    float* out = (float*)d_out;
    dim3 grid((OW + TILE - 1) / TILE, (OH + TILE - 1) / TILE, 8 * 64);
    dim3 block(256);
    hipLaunchKernelGGL(lpf_kernel, grid, block, 0, stream, x, out);
}